// Round 7
// baseline (186.342 us; speedup 1.0000x reference)
//
#include <hip/hip_runtime.h>

typedef unsigned short u16;
typedef float f32x4 __attribute__((ext_vector_type(4)));
typedef short bf16x8 __attribute__((ext_vector_type(8)));
typedef u16 u16x4 __attribute__((ext_vector_type(4)));
typedef u16 u16x8 __attribute__((ext_vector_type(8)));
typedef __bf16 bfr4 __attribute__((ext_vector_type(4)));

// ---- constants ----
#define BB 2
#define NN 2048
#define CC 1024
#define HH 16
#define DD 64
#define MM (BB * NN)          // 4096 rows
#define NQKV (3 * CC)         // 3072
#define QSCALE 0.18033688011112042f   // 0.125 * log2(e): scores in log2 domain

#if __has_builtin(__builtin_amdgcn_exp2f)
#define EXP2(x) __builtin_amdgcn_exp2f(x)
#else
#define EXP2(x) exp2f(x)
#endif

__device__ __forceinline__ u16 f2bf(float f) {
    unsigned u = __float_as_uint(f);
    u += 0x7FFFu + ((u >> 16) & 1u);   // round-to-nearest-even
    return (u16)(u >> 16);
}

// async global->LDS, 16B per lane. LDS dst must be wave-uniform-base + lane*16.
__device__ __forceinline__ void ld_lds16(const u16* g, u16* l) {
    __builtin_amdgcn_global_load_lds(
        (const __attribute__((address_space(1))) unsigned int*)g,
        (__attribute__((address_space(3))) unsigned int*)l, 16, 0, 0);
}

// ---- fused prep: x fp32->bf16 cast + both weight transpose-casts ----
// blocks [0,2048): tobf of x; [2048,5120): tcast w_qkv; [5120,6144): tcast w_proj
__global__ __launch_bounds__(256) void k_prep(const float* __restrict__ x,
                                              const float* __restrict__ wqkv,
                                              const float* __restrict__ wproj,
                                              u16* __restrict__ Xb,
                                              u16* __restrict__ Wq,
                                              u16* __restrict__ Wp) {
    __shared__ float tile[32][33];
    int bid = blockIdx.x, t = threadIdx.x;
    if (bid < 2048) {
        int i = (bid * 256 + t) * 8;
        float4 a = *(const float4*)(x + i);
        float4 b = *(const float4*)(x + i + 4);
        u16x8 o;
        o[0] = f2bf(a.x); o[1] = f2bf(a.y); o[2] = f2bf(a.z); o[3] = f2bf(a.w);
        o[4] = f2bf(b.x); o[5] = f2bf(b.y); o[6] = f2bf(b.z); o[7] = f2bf(b.w);
        *(u16x8*)(Xb + i) = o;
        return;
    }
    const float* in;
    u16* out;
    int Nn, n0, k0;
    if (bid < 2048 + 3072) {
        int b2 = bid - 2048;
        in = wqkv; out = Wq; Nn = NQKV;
        n0 = (b2 % 96) * 32; k0 = (b2 / 96) * 32;
    } else {
        int b3 = bid - 5120;
        in = wproj; out = Wp; Nn = CC;
        n0 = (b3 & 31) * 32; k0 = (b3 >> 5) * 32;
    }
    int tx = t & 31, ty = t >> 5;
#pragma unroll
    for (int r = 0; r < 32; r += 8)
        tile[ty + r][tx] = in[(size_t)(k0 + ty + r) * Nn + n0 + tx];
    __syncthreads();
#pragma unroll
    for (int r = 0; r < 32; r += 8)
        out[(size_t)(n0 + ty + r) * CC + k0 + tx] = f2bf(tile[tx][ty + r]);
}

// ---- QKV GEMM: C = A @ B^T, K=1024, 256x192 tile, BK=64, 8 waves (2Mx4N) ----
// R6 structure (unchanged): per-wave 128x48 (acc 8x3), 48 MFMA/barrier/wave,
// grid 16x16 = 256 blocks = 1 block/CU, 2-phase dbuf ping-pong, LDS 112 KB,
// XCD-chunked bijective swizzle.
__global__ __launch_bounds__(512, 2) void k_gemmq(
    const u16* __restrict__ A, const u16* __restrict__ B,
    u16* __restrict__ Qb, u16* __restrict__ Kb, u16* __restrict__ Vb) {
    const int Kd = 1024;
    __shared__ __align__(16) u16 Ah0[256][64], Bh0[192][64];
    __shared__ __align__(16) u16 Ah1[256][64], Bh1[192][64];

    int t = threadIdx.x, wave = t >> 6, lane = t & 63;
    int quad = lane >> 4, l16 = lane & 15;
    int wr = wave >> 2, wc = wave & 3;          // 2 x 4 wave grid

    // XCD-chunked bijective swizzle: 256 blocks = 8 XCDs x 32 contiguous
    int cid = blockIdx.y * 16 + blockIdx.x;
    int swz = (cid & 7) * 32 + (cid >> 3);
    int m0 = (swz >> 4) * 256, n0 = (swz & 15) * 192;

    // staging: 8 waves x 8 rows = 64 rows per issue; row&7 == lane>>3
    int strow = wave * 8 + (lane >> 3);
    int stdst = (lane & 7) * 8;                      // lds col (u16), linear
    int stsrc = ((lane & 7) ^ (lane >> 3)) * 8;      // pre-swizzled global col

    f32x4 acc[8][3];
#pragma unroll
    for (int i = 0; i < 8; i++)
#pragma unroll
        for (int j = 0; j < 3; j++) acc[i][j] = f32x4{0.f, 0.f, 0.f, 0.f};

    auto STAGE = [&](int k0, u16 (*Ad)[64], u16 (*Bd)[64]) {
#pragma unroll
        for (int i = 0; i < 4; i++) {
            int row = i * 64 + strow;
            ld_lds16(A + (size_t)(m0 + row) * Kd + k0 + stsrc, &Ad[row][stdst]);
        }
#pragma unroll
        for (int i = 0; i < 3; i++) {
            int row = i * 64 + strow;
            ld_lds16(B + (size_t)(n0 + row) * Kd + k0 + stsrc, &Bd[row][stdst]);
        }
    };
    auto COMPUTE = [&](u16 (*As)[64], u16 (*Bs)[64]) {
#pragma unroll
        for (int s = 0; s < 2; s++) {                // two K=32 sub-steps
            int pos = ((s * 4 + quad) ^ (l16 & 7)) * 8;   // swizzled col (u16)
            bf16x8 af[8], bg[3];
#pragma unroll
            for (int m = 0; m < 8; m++)
                af[m] = *(const bf16x8*)&As[wr * 128 + m * 16 + l16][pos];
#pragma unroll
            for (int n = 0; n < 3; n++)
                bg[n] = *(const bf16x8*)&Bs[wc * 48 + n * 16 + l16][pos];
            __builtin_amdgcn_s_setprio(1);
#pragma unroll
            for (int m = 0; m < 8; m++)
#pragma unroll
                for (int n = 0; n < 3; n++)
                    acc[m][n] = __builtin_amdgcn_mfma_f32_16x16x32_bf16(
                        af[m], bg[n], acc[m][n], 0, 0, 0);
            __builtin_amdgcn_s_setprio(0);
        }
    };

    STAGE(0, Ah0, Bh0);
    __syncthreads();   // implicit vmcnt(0): tile 0 ready
    for (int k0 = 0; k0 < Kd; k0 += 128) {
        STAGE(k0 + 64, Ah1, Bh1);          // latency hides under compute on buf0
        COMPUTE(Ah0, Bh0);
        __syncthreads();                   // buf1 ready, buf0 free
        if (k0 + 128 < Kd) STAGE(k0 + 128, Ah0, Bh0);
        COMPUTE(Ah1, Bh1);
        __syncthreads();                   // buf0 ready, buf1 free
    }

    // QKV scatter epilogue: Q*QSCALE,K -> [BH,N,D]; V^T -> [BH,D,N]
#pragma unroll
    for (int m = 0; m < 8; m++)
#pragma unroll
        for (int n = 0; n < 3; n++)
#pragma unroll
            for (int r = 0; r < 4; r++) {
                int grow = m0 + wr * 128 + m * 16 + quad * 4 + r;
                int gcol = n0 + wc * 48 + n * 16 + l16;
                float v = acc[m][n][r];
                int three = gcol >> 10, rem = gcol & 1023;
                int h = rem >> 6, d = rem & 63;
                int bb = grow >> 11, nn = grow & 2047;
                if (three == 0) {
                    Qb[((size_t)(bb * HH + h) * NN + nn) * DD + d] = f2bf(v * QSCALE);
                } else if (three == 1) {
                    Kb[((size_t)(bb * HH + h) * NN + nn) * DD + d] = f2bf(v);
                } else {
                    Vb[((size_t)(bb * HH + h) * DD + d) * NN + nn] = f2bf(v);
                }
            }
}

// ---- proj GEMM: C = A @ B^T + bias, K=1024, 64x128 tile, BK=64, 4 waves ----
// R7: grid swapped to (m=64 on x, n=8 on y). Hardware XCD = linear_id & 7;
//     with m on x, XCD x owns m-tiles {x, x+8, ...} (8 panels, 1 MB) -> A
//     (Ob) is read ~once per XCD instead of 64 panels/XCD (was id&7 = n-idx:
//     each XCD streamed the full 8 MB Ob). B (Wp, 2 MB) L2-resident either way.
__global__ __launch_bounds__(256) void k_gemmp(
    const u16* __restrict__ A, const u16* __restrict__ B,
    const float* __restrict__ bias, float* __restrict__ Cout) {
    const int Kd = 1024;
    __shared__ __align__(16) u16 Ah0[64][64], Bh0[128][64];
    __shared__ __align__(16) u16 Ah1[64][64], Bh1[128][64];

    int t = threadIdx.x, wave = t >> 6, lane = t & 63;
    int quad = lane >> 4, l16 = lane & 15;
    int m0 = blockIdx.x * 64, n0 = blockIdx.y * 128;

    // staging: 4 waves x 8 rows = 32 rows per issue; row&7 == lane>>3
    int strow = wave * 8 + (lane >> 3);
    int stdst = (lane & 7) * 8;
    int stsrc = ((lane & 7) ^ (lane >> 3)) * 8;

    f32x4 acc[4][2];
#pragma unroll
    for (int i = 0; i < 4; i++)
#pragma unroll
        for (int j = 0; j < 2; j++) acc[i][j] = f32x4{0.f, 0.f, 0.f, 0.f};

    auto STAGE = [&](int k0, u16 (*Ad)[64], u16 (*Bd)[64]) {
#pragma unroll
        for (int i = 0; i < 2; i++) {
            int row = i * 32 + strow;
            ld_lds16(A + (size_t)(m0 + row) * Kd + k0 + stsrc, &Ad[row][stdst]);
        }
#pragma unroll
        for (int i = 0; i < 4; i++) {
            int row = i * 32 + strow;
            ld_lds16(B + (size_t)(n0 + row) * Kd + k0 + stsrc, &Bd[row][stdst]);
        }
    };
    auto COMPUTE = [&](u16 (*As)[64], u16 (*Bs)[64]) {
#pragma unroll
        for (int s = 0; s < 2; s++) {
            int pos = ((s * 4 + quad) ^ (l16 & 7)) * 8;
            bf16x8 af[4], bg[2];
#pragma unroll
            for (int m = 0; m < 4; m++)
                af[m] = *(const bf16x8*)&As[m * 16 + l16][pos];
#pragma unroll
            for (int n = 0; n < 2; n++)
                bg[n] = *(const bf16x8*)&Bs[wave * 32 + n * 16 + l16][pos];
            __builtin_amdgcn_s_setprio(1);
#pragma unroll
            for (int m = 0; m < 4; m++)
#pragma unroll
                for (int n = 0; n < 2; n++)
                    acc[m][n] = __builtin_amdgcn_mfma_f32_16x16x32_bf16(
                        af[m], bg[n], acc[m][n], 0, 0, 0);
            __builtin_amdgcn_s_setprio(0);
        }
    };

    STAGE(0, Ah0, Bh0);
    __syncthreads();
    for (int k0 = 0; k0 < Kd; k0 += 128) {
        STAGE(k0 + 64, Ah1, Bh1);
        COMPUTE(Ah0, Bh0);
        __syncthreads();
        if (k0 + 128 < Kd) STAGE(k0 + 128, Ah0, Bh0);
        COMPUTE(Ah1, Bh1);
        __syncthreads();
    }

#pragma unroll
    for (int m = 0; m < 4; m++)
#pragma unroll
        for (int n = 0; n < 2; n++)
#pragma unroll
            for (int r = 0; r < 4; r++) {
                int grow = m0 + m * 16 + quad * 4 + r;
                int gcol = n0 + wave * 32 + n * 16 + l16;
                Cout[(size_t)grow * CC + gcol] = acc[m][n][r] + bias[gcol];
            }
}

// ---- flash attention, S^T formulation, no-max softmax (exp2 domain) ----
// Q,K: [BH][N][D] bf16 (Q pre-scaled by 0.125*log2e); V^T: [BH][D][N]
// out Ob bf16 [M][C]
// R7: grid swapped to (bh=32 on x, q=16 on y). Hardware XCD = linear_id & 7;
//     with bh on x, all 16 q-blocks of a head land on ONE XCD -> per-XCD K/V
//     working set = 4 heads x 512 KB = 2 MB <= 4 MB L2. Was: q on x spread
//     each head's blocks over all 8 XCDs -> 8-way K/V L2 replication,
//     FETCH_SIZE 69.7 MB vs ~24 MB ideal. Compute structure unchanged (R2).
__global__ __launch_bounds__(512) void k_attn(const u16* __restrict__ Qb,
                                              const u16* __restrict__ Kb,
                                              const u16* __restrict__ VbT,
                                              u16* __restrict__ Ob) {
    __shared__ __align__(16) u16 Ks0[64][64], Ks1[64][64];   // swizzled
    __shared__ __align__(16) u16 Vs0[64][64], Vs1[64][64];
    __shared__ __align__(16) u16 Ps[8][16][72];              // per-wave P^T, padded

    int t = threadIdx.x, wave = t >> 6, lane = t & 63;
    int quad = lane >> 4, l16 = lane & 15;
    int bh = blockIdx.x, q0 = blockIdx.y * 128;
    const size_t kbase = (size_t)bh * NN * DD;
    const size_t vbase = (size_t)bh * DD * NN;

    int qrow = q0 + wave * 16 + l16;
    bf16x8 qf0 = *(const bf16x8*)&Qb[kbase + (size_t)qrow * DD + quad * 8];
    bf16x8 qf1 = *(const bf16x8*)&Qb[kbase + (size_t)qrow * DD + 32 + quad * 8];

    f32x4 o[4];
#pragma unroll
    for (int i = 0; i < 4; i++) o[i] = f32x4{0.f, 0.f, 0.f, 0.f};
    f32x4 lrow = f32x4{0.f, 0.f, 0.f, 0.f};   // 4 independent sum chains

    int stgrp = lane & 7;
    int stsrc = (stgrp ^ (lane >> 3)) * 8;     // swizzled global col (u16)
    int strow = wave * 8 + (lane >> 3);        // 8 waves x 8 rows = 64
    int cf0 = (quad ^ (l16 & 7)) * 8;
    int cf1 = ((4 + quad) ^ (l16 & 7)) * 8;

    // per wave: one K row-group + one V row-group (1KB each, linear lane*16 dst)
    auto STAGE = [&](int cc, u16 (*Kd_)[64], u16 (*Vd_)[64]) {
        ld_lds16(&Kb[kbase + (size_t)(cc * 64 + strow) * DD + stsrc],
                 &Kd_[strow][stgrp * 8]);
        ld_lds16(&VbT[vbase + (size_t)strow * NN + cc * 64 + stsrc],
                 &Vd_[strow][stgrp * 8]);
    };

    auto COMPUTE = [&](u16 (*Ksrc)[64], u16 (*Vsrc)[64]) {
        bf16x8 kf[4][2];
#pragma unroll
        for (int kt = 0; kt < 4; kt++) {
            kf[kt][0] = *(const bf16x8*)&Ksrc[kt * 16 + l16][cf0];
            kf[kt][1] = *(const bf16x8*)&Ksrc[kt * 16 + l16][cf1];
        }
        f32x4 s[4];
        __builtin_amdgcn_s_setprio(1);
#pragma unroll
        for (int kt = 0; kt < 4; kt++) {
            f32x4 z = f32x4{0.f, 0.f, 0.f, 0.f};
            z = __builtin_amdgcn_mfma_f32_16x16x32_bf16(kf[kt][0], qf0, z, 0, 0, 0);
            z = __builtin_amdgcn_mfma_f32_16x16x32_bf16(kf[kt][1], qf1, z, 0, 0, 0);
            s[kt] = z;   // rows k = kt*16+quad*4+r, col q = l16
        }
        __builtin_amdgcn_s_setprio(0);
        // p = exp2(s) (scores pre-scaled by log2e): no max, no rescale.
#pragma unroll
        for (int kt = 0; kt < 4; kt++) {
            bfr4 pk;
#pragma unroll
            for (int r = 0; r < 4; r++) {
                float e = EXP2(s[kt][r]);
                lrow[r] += e;              // 4 independent chains
                pk[r] = (__bf16)e;         // RTNE; v_cvt_pk_bf16_f32
            }
            *(bfr4*)&Ps[wave][l16][kt * 16 + quad * 4] = pk;
        }
        // wave-local DS write->read ordering
        __asm__ volatile("s_waitcnt lgkmcnt(0)" ::: "memory");
        bf16x8 pb0 = *(const bf16x8*)&Ps[wave][l16][quad * 8];
        bf16x8 pb1 = *(const bf16x8*)&Ps[wave][l16][32 + quad * 8];
        __builtin_amdgcn_s_setprio(1);
#pragma unroll
        for (int dt = 0; dt < 4; dt++) {
            bf16x8 vf0 = *(const bf16x8*)&Vsrc[dt * 16 + l16][cf0];
            bf16x8 vf1 = *(const bf16x8*)&Vsrc[dt * 16 + l16][cf1];
            o[dt] = __builtin_amdgcn_mfma_f32_16x16x32_bf16(vf0, pb0, o[dt], 0, 0, 0);
            o[dt] = __builtin_amdgcn_mfma_f32_16x16x32_bf16(vf1, pb1, o[dt], 0, 0, 0);
        }
        __builtin_amdgcn_s_setprio(0);
    };

    STAGE(0, Ks0, Vs0);
    __syncthreads();   // implicit vmcnt(0): tile 0 ready

    for (int c = 0; c < NN / 64; c += 2) {
        STAGE(c + 1, Ks1, Vs1);            // hides under compute on buf0
        COMPUTE(Ks0, Vs0);
        __syncthreads();                   // drains vmcnt: buf1 ready, buf0 free
        if (c + 2 < NN / 64) STAGE(c + 2, Ks0, Vs0);
        COMPUTE(Ks1, Vs1);
        __syncthreads();                   // buf0 ready, buf1 free
    }

    int b = bh >> 4, h = bh & 15;
    // horizontal sum of the 4 chains, then reduce across quads
    float l = (lrow[0] + lrow[1]) + (lrow[2] + lrow[3]);
    l += __shfl_xor(l, 16, 64);
    l += __shfl_xor(l, 32, 64);
    float inv = 1.f / l;
    int grow = b * NN + q0 + wave * 16 + l16;
#pragma unroll
    for (int dt = 0; dt < 4; dt++) {
        u16x4 hv;
#pragma unroll
        for (int r = 0; r < 4; r++) hv[r] = f2bf(o[dt][r] * inv);
        int gcol = h * DD + dt * 16 + quad * 4;
        *(u16x4*)&Ob[(size_t)grow * CC + gcol] = hv;
    }
}

extern "C" void kernel_launch(void* const* d_in, const int* in_sizes, int n_in,
                              void* d_out, int out_size, void* d_ws, size_t ws_size,
                              hipStream_t stream) {
    const float* x      = (const float*)d_in[0];
    const float* w_qkv  = (const float*)d_in[1];
    const float* w_proj = (const float*)d_in[2];
    const float* b_proj = (const float*)d_in[3];
    float* out = (float*)d_out;

    u16* p = (u16*)d_ws;
    u16* Xb = p; p += (size_t)MM * CC;
    u16* Wq = p; p += (size_t)NQKV * CC;
    u16* Wp = p; p += (size_t)CC * CC;
    u16* Qb = p; p += (size_t)MM * CC;
    u16* Kb = p; p += (size_t)MM * CC;
    u16* Vb = p; p += (size_t)MM * CC;           // V^T [BH][D][N]
    u16* Ob = p; p += (size_t)MM * CC;

    k_prep<<<2048 + 3072 + 1024, 256, 0, stream>>>(x, w_qkv, w_proj, Xb, Wq, Wp);
    k_gemmq<<<dim3(NQKV / 192, MM / 256), 512, 0, stream>>>(Xb, Wq, Qb, Kb, Vb);
    // bh on x: linear id & 7 == bh & 7 -> one XCD per head group (K/V L2-resident)
    k_attn<<<dim3(BB * HH, NN / 128), 512, 0, stream>>>(Qb, Kb, Vb, Ob);
    // m on x: each XCD owns 8 m-panels of Ob instead of streaming all 64
    k_gemmp<<<dim3(MM / 64, CC / 128), 256, 0, stream>>>(Ob, Wp, b_proj, out);
}

// Round 8
// 184.300 us; speedup vs baseline: 1.0111x; 1.0111x over previous
//
#include <hip/hip_runtime.h>

typedef unsigned short u16;
typedef float f32x4 __attribute__((ext_vector_type(4)));
typedef short bf16x8 __attribute__((ext_vector_type(8)));
typedef u16 u16x4 __attribute__((ext_vector_type(4)));
typedef u16 u16x8 __attribute__((ext_vector_type(8)));
typedef __bf16 bfr4 __attribute__((ext_vector_type(4)));

// ---- constants ----
#define BB 2
#define NN 2048
#define CC 1024
#define HH 16
#define DD 64
#define MM (BB * NN)          // 4096 rows
#define NQKV (3 * CC)         // 3072
#define QSCALE 0.18033688011112042f   // 0.125 * log2(e): scores in log2 domain

#if __has_builtin(__builtin_amdgcn_exp2f)
#define EXP2(x) __builtin_amdgcn_exp2f(x)
#else
#define EXP2(x) exp2f(x)
#endif

__device__ __forceinline__ u16 f2bf(float f) {
    unsigned u = __float_as_uint(f);
    u += 0x7FFFu + ((u >> 16) & 1u);   // round-to-nearest-even
    return (u16)(u >> 16);
}

// async global->LDS, 16B per lane. LDS dst must be wave-uniform-base + lane*16.
__device__ __forceinline__ void ld_lds16(const u16* g, u16* l) {
    __builtin_amdgcn_global_load_lds(
        (const __attribute__((address_space(1))) unsigned int*)g,
        (__attribute__((address_space(3))) unsigned int*)l, 16, 0, 0);
}

// ---- fused prep: x fp32->bf16 cast + both weight transpose-casts ----
// blocks [0,2048): tobf of x; [2048,5120): tcast w_qkv; [5120,6144): tcast w_proj
__global__ __launch_bounds__(256) void k_prep(const float* __restrict__ x,
                                              const float* __restrict__ wqkv,
                                              const float* __restrict__ wproj,
                                              u16* __restrict__ Xb,
                                              u16* __restrict__ Wq,
                                              u16* __restrict__ Wp) {
    __shared__ float tile[32][33];
    int bid = blockIdx.x, t = threadIdx.x;
    if (bid < 2048) {
        int i = (bid * 256 + t) * 8;
        float4 a = *(const float4*)(x + i);
        float4 b = *(const float4*)(x + i + 4);
        u16x8 o;
        o[0] = f2bf(a.x); o[1] = f2bf(a.y); o[2] = f2bf(a.z); o[3] = f2bf(a.w);
        o[4] = f2bf(b.x); o[5] = f2bf(b.y); o[6] = f2bf(b.z); o[7] = f2bf(b.w);
        *(u16x8*)(Xb + i) = o;
        return;
    }
    const float* in;
    u16* out;
    int Nn, n0, k0;
    if (bid < 2048 + 3072) {
        int b2 = bid - 2048;
        in = wqkv; out = Wq; Nn = NQKV;
        n0 = (b2 % 96) * 32; k0 = (b2 / 96) * 32;
    } else {
        int b3 = bid - 5120;
        in = wproj; out = Wp; Nn = CC;
        n0 = (b3 & 31) * 32; k0 = (b3 >> 5) * 32;
    }
    int tx = t & 31, ty = t >> 5;
#pragma unroll
    for (int r = 0; r < 32; r += 8)
        tile[ty + r][tx] = in[(size_t)(k0 + ty + r) * Nn + n0 + tx];
    __syncthreads();
#pragma unroll
    for (int r = 0; r < 32; r += 8)
        out[(size_t)(n0 + ty + r) * CC + k0 + tx] = f2bf(tile[tx][ty + r]);
}

// ---- QKV GEMM: C = A @ B^T, K=1024, 256x192 tile, BK=64, 8 waves (2Mx4N) ----
// R6 structure (unchanged): per-wave 128x48 (acc 8x3), 48 MFMA/barrier/wave,
// grid 16x16 = 256 blocks = 1 block/CU, 2-phase dbuf ping-pong, LDS 112 KB,
// XCD-chunked bijective swizzle.
__global__ __launch_bounds__(512, 2) void k_gemmq(
    const u16* __restrict__ A, const u16* __restrict__ B,
    u16* __restrict__ Qb, u16* __restrict__ Kb, u16* __restrict__ Vb) {
    const int Kd = 1024;
    __shared__ __align__(16) u16 Ah0[256][64], Bh0[192][64];
    __shared__ __align__(16) u16 Ah1[256][64], Bh1[192][64];

    int t = threadIdx.x, wave = t >> 6, lane = t & 63;
    int quad = lane >> 4, l16 = lane & 15;
    int wr = wave >> 2, wc = wave & 3;          // 2 x 4 wave grid

    // XCD-chunked bijective swizzle: 256 blocks = 8 XCDs x 32 contiguous
    int cid = blockIdx.y * 16 + blockIdx.x;
    int swz = (cid & 7) * 32 + (cid >> 3);
    int m0 = (swz >> 4) * 256, n0 = (swz & 15) * 192;

    // staging: 8 waves x 8 rows = 64 rows per issue; row&7 == lane>>3
    int strow = wave * 8 + (lane >> 3);
    int stdst = (lane & 7) * 8;                      // lds col (u16), linear
    int stsrc = ((lane & 7) ^ (lane >> 3)) * 8;      // pre-swizzled global col

    f32x4 acc[8][3];
#pragma unroll
    for (int i = 0; i < 8; i++)
#pragma unroll
        for (int j = 0; j < 3; j++) acc[i][j] = f32x4{0.f, 0.f, 0.f, 0.f};

    auto STAGE = [&](int k0, u16 (*Ad)[64], u16 (*Bd)[64]) {
#pragma unroll
        for (int i = 0; i < 4; i++) {
            int row = i * 64 + strow;
            ld_lds16(A + (size_t)(m0 + row) * Kd + k0 + stsrc, &Ad[row][stdst]);
        }
#pragma unroll
        for (int i = 0; i < 3; i++) {
            int row = i * 64 + strow;
            ld_lds16(B + (size_t)(n0 + row) * Kd + k0 + stsrc, &Bd[row][stdst]);
        }
    };
    auto COMPUTE = [&](u16 (*As)[64], u16 (*Bs)[64]) {
#pragma unroll
        for (int s = 0; s < 2; s++) {                // two K=32 sub-steps
            int pos = ((s * 4 + quad) ^ (l16 & 7)) * 8;   // swizzled col (u16)
            bf16x8 af[8], bg[3];
#pragma unroll
            for (int m = 0; m < 8; m++)
                af[m] = *(const bf16x8*)&As[wr * 128 + m * 16 + l16][pos];
#pragma unroll
            for (int n = 0; n < 3; n++)
                bg[n] = *(const bf16x8*)&Bs[wc * 48 + n * 16 + l16][pos];
            __builtin_amdgcn_s_setprio(1);
#pragma unroll
            for (int m = 0; m < 8; m++)
#pragma unroll
                for (int n = 0; n < 3; n++)
                    acc[m][n] = __builtin_amdgcn_mfma_f32_16x16x32_bf16(
                        af[m], bg[n], acc[m][n], 0, 0, 0);
            __builtin_amdgcn_s_setprio(0);
        }
    };

    STAGE(0, Ah0, Bh0);
    __syncthreads();   // implicit vmcnt(0): tile 0 ready
    for (int k0 = 0; k0 < Kd; k0 += 128) {
        STAGE(k0 + 64, Ah1, Bh1);          // latency hides under compute on buf0
        COMPUTE(Ah0, Bh0);
        __syncthreads();                   // buf1 ready, buf0 free
        if (k0 + 128 < Kd) STAGE(k0 + 128, Ah0, Bh0);
        COMPUTE(Ah1, Bh1);
        __syncthreads();                   // buf0 ready, buf1 free
    }

    // QKV scatter epilogue: Q*QSCALE,K -> [BH,N,D]; V^T -> [BH,D,N]
#pragma unroll
    for (int m = 0; m < 8; m++)
#pragma unroll
        for (int n = 0; n < 3; n++)
#pragma unroll
            for (int r = 0; r < 4; r++) {
                int grow = m0 + wr * 128 + m * 16 + quad * 4 + r;
                int gcol = n0 + wc * 48 + n * 16 + l16;
                float v = acc[m][n][r];
                int three = gcol >> 10, rem = gcol & 1023;
                int h = rem >> 6, d = rem & 63;
                int bb = grow >> 11, nn = grow & 2047;
                if (three == 0) {
                    Qb[((size_t)(bb * HH + h) * NN + nn) * DD + d] = f2bf(v * QSCALE);
                } else if (three == 1) {
                    Kb[((size_t)(bb * HH + h) * NN + nn) * DD + d] = f2bf(v);
                } else {
                    Vb[((size_t)(bb * HH + h) * DD + d) * NN + nn] = f2bf(v);
                }
            }
}

// ---- proj GEMM: C = A @ B^T + bias, K=1024 ----
// R8: 64x128 tile, BK=128, SINGLE-buffered, 4 waves (1Mx4N).
//     Old shape (BK=64 dbuf, acc 4x2) had only 8 MFMA per K=32 substep --
//     the R3 thinness disease; suspected ~40-55 us (never surfaced in top-5).
//     Now per barrier-pair: 4 substeps x 8 MFMA = 32 MFMA + 24 ds_read/wave.
//     LDS 48 KB -> 3 blocks/CU by LDS; grid 64x8 = 512 = 2 blocks/CU ->
//     cross-block overlap covers the exposed stage latency (m97 mechanism).
//     m on blockIdx.x: XCD owns 8 contiguous m-panels of A (L2 locality).
__global__ __launch_bounds__(256) void k_gemmp(
    const u16* __restrict__ A, const u16* __restrict__ B,
    const float* __restrict__ bias, float* __restrict__ Cout) {
    const int Kd = 1024;
    __shared__ __align__(16) u16 Ah[64][128];
    __shared__ __align__(16) u16 Bh[128][128];

    int t = threadIdx.x, wave = t >> 6, lane = t & 63;
    int quad = lane >> 4, l16 = lane & 15;
    int m0 = blockIdx.x * 64, n0 = blockIdx.y * 128;

    // staging: per instr, 4 rows (16 lanes each); 16-group rows, XOR row&7
    int strow = lane >> 4;                       // row within 4-row instr chunk
    int stdst = (lane & 15) * 8;                 // linear lds col (u16)

    f32x4 acc[4][2];
#pragma unroll
    for (int i = 0; i < 4; i++)
#pragma unroll
        for (int j = 0; j < 2; j++) acc[i][j] = f32x4{0.f, 0.f, 0.f, 0.f};

    auto STAGE = [&](int k0) {
        // A rows [wave*16, wave*16+16): 4 instrs
#pragma unroll
        for (int i = 0; i < 4; i++) {
            int row = wave * 16 + i * 4 + strow;
            int src = ((lane & 15) ^ (row & 7)) * 8;   // pre-swizzled global col
            ld_lds16(A + (size_t)(m0 + row) * Kd + k0 + src, &Ah[row & 63][0] + stdst);
        }
        // B rows [wave*32, wave*32+32): 8 instrs
#pragma unroll
        for (int i = 0; i < 8; i++) {
            int row = wave * 32 + i * 4 + strow;
            int src = ((lane & 15) ^ (row & 7)) * 8;
            ld_lds16(B + (size_t)(n0 + row) * Kd + k0 + src, &Bh[row & 127][0] + stdst);
        }
    };
    auto COMPUTE = [&]() {
#pragma unroll
        for (int s = 0; s < 4; s++) {              // four K=32 sub-steps
            int pos = ((s * 4 + quad) ^ (l16 & 7)) * 8;   // swizzled col group
            bf16x8 af[4], bg[2];
#pragma unroll
            for (int m = 0; m < 4; m++)
                af[m] = *(const bf16x8*)&Ah[m * 16 + l16][pos];
#pragma unroll
            for (int n = 0; n < 2; n++)
                bg[n] = *(const bf16x8*)&Bh[wave * 32 + n * 16 + l16][pos];
            __builtin_amdgcn_s_setprio(1);
#pragma unroll
            for (int m = 0; m < 4; m++)
#pragma unroll
                for (int n = 0; n < 2; n++)
                    acc[m][n] = __builtin_amdgcn_mfma_f32_16x16x32_bf16(
                        af[m], bg[n], acc[m][n], 0, 0, 0);
            __builtin_amdgcn_s_setprio(0);
        }
    };

    for (int k0 = 0; k0 < Kd; k0 += 128) {
        __syncthreads();      // all reads of previous tile done (buf free)
        STAGE(k0);
        __syncthreads();      // implicit vmcnt(0): tile ready
        COMPUTE();
    }

#pragma unroll
    for (int m = 0; m < 4; m++)
#pragma unroll
        for (int n = 0; n < 2; n++)
#pragma unroll
            for (int r = 0; r < 4; r++) {
                int grow = m0 + m * 16 + quad * 4 + r;
                int gcol = n0 + wave * 32 + n * 16 + l16;
                Cout[(size_t)grow * CC + gcol] = acc[m][n][r] + bias[gcol];
            }
}

// ---- flash attention, S^T formulation, no-max softmax (exp2 domain) ----
// Q,K: [BH][N][D] bf16 (Q pre-scaled by 0.125*log2e); V^T: [BH][D][N]
// out Ob bf16 [M][C]
// R7 structure (unchanged): bh on x -> one XCD per head-group (K/V L2-resident);
// 8 waves / 512 threads, static dbuf, prefetch-before-compute, one barrier/tile.
__global__ __launch_bounds__(512) void k_attn(const u16* __restrict__ Qb,
                                              const u16* __restrict__ Kb,
                                              const u16* __restrict__ VbT,
                                              u16* __restrict__ Ob) {
    __shared__ __align__(16) u16 Ks0[64][64], Ks1[64][64];   // swizzled
    __shared__ __align__(16) u16 Vs0[64][64], Vs1[64][64];
    __shared__ __align__(16) u16 Ps[8][16][72];              // per-wave P^T, padded

    int t = threadIdx.x, wave = t >> 6, lane = t & 63;
    int quad = lane >> 4, l16 = lane & 15;
    int bh = blockIdx.x, q0 = blockIdx.y * 128;
    const size_t kbase = (size_t)bh * NN * DD;
    const size_t vbase = (size_t)bh * DD * NN;

    int qrow = q0 + wave * 16 + l16;
    bf16x8 qf0 = *(const bf16x8*)&Qb[kbase + (size_t)qrow * DD + quad * 8];
    bf16x8 qf1 = *(const bf16x8*)&Qb[kbase + (size_t)qrow * DD + 32 + quad * 8];

    f32x4 o[4];
#pragma unroll
    for (int i = 0; i < 4; i++) o[i] = f32x4{0.f, 0.f, 0.f, 0.f};
    f32x4 lrow = f32x4{0.f, 0.f, 0.f, 0.f};   // 4 independent sum chains

    int stgrp = lane & 7;
    int stsrc = (stgrp ^ (lane >> 3)) * 8;     // swizzled global col (u16)
    int strow = wave * 8 + (lane >> 3);        // 8 waves x 8 rows = 64
    int cf0 = (quad ^ (l16 & 7)) * 8;
    int cf1 = ((4 + quad) ^ (l16 & 7)) * 8;

    // per wave: one K row-group + one V row-group (1KB each, linear lane*16 dst)
    auto STAGE = [&](int cc, u16 (*Kd_)[64], u16 (*Vd_)[64]) {
        ld_lds16(&Kb[kbase + (size_t)(cc * 64 + strow) * DD + stsrc],
                 &Kd_[strow][stgrp * 8]);
        ld_lds16(&VbT[vbase + (size_t)strow * NN + cc * 64 + stsrc],
                 &Vd_[strow][stgrp * 8]);
    };

    auto COMPUTE = [&](u16 (*Ksrc)[64], u16 (*Vsrc)[64]) {
        bf16x8 kf[4][2];
#pragma unroll
        for (int kt = 0; kt < 4; kt++) {
            kf[kt][0] = *(const bf16x8*)&Ksrc[kt * 16 + l16][cf0];
            kf[kt][1] = *(const bf16x8*)&Ksrc[kt * 16 + l16][cf1];
        }
        f32x4 s[4];
        __builtin_amdgcn_s_setprio(1);
#pragma unroll
        for (int kt = 0; kt < 4; kt++) {
            f32x4 z = f32x4{0.f, 0.f, 0.f, 0.f};
            z = __builtin_amdgcn_mfma_f32_16x16x32_bf16(kf[kt][0], qf0, z, 0, 0, 0);
            z = __builtin_amdgcn_mfma_f32_16x16x32_bf16(kf[kt][1], qf1, z, 0, 0, 0);
            s[kt] = z;   // rows k = kt*16+quad*4+r, col q = l16
        }
        __builtin_amdgcn_s_setprio(0);
        // p = exp2(s) (scores pre-scaled by log2e): no max, no rescale.
#pragma unroll
        for (int kt = 0; kt < 4; kt++) {
            bfr4 pk;
#pragma unroll
            for (int r = 0; r < 4; r++) {
                float e = EXP2(s[kt][r]);
                lrow[r] += e;              // 4 independent chains
                pk[r] = (__bf16)e;         // RTNE; v_cvt_pk_bf16_f32
            }
            *(bfr4*)&Ps[wave][l16][kt * 16 + quad * 4] = pk;
        }
        // wave-local DS write->read ordering
        __asm__ volatile("s_waitcnt lgkmcnt(0)" ::: "memory");
        bf16x8 pb0 = *(const bf16x8*)&Ps[wave][l16][quad * 8];
        bf16x8 pb1 = *(const bf16x8*)&Ps[wave][l16][32 + quad * 8];
        __builtin_amdgcn_s_setprio(1);
#pragma unroll
        for (int dt = 0; dt < 4; dt++) {
            bf16x8 vf0 = *(const bf16x8*)&Vsrc[dt * 16 + l16][cf0];
            bf16x8 vf1 = *(const bf16x8*)&Vsrc[dt * 16 + l16][cf1];
            o[dt] = __builtin_amdgcn_mfma_f32_16x16x32_bf16(vf0, pb0, o[dt], 0, 0, 0);
            o[dt] = __builtin_amdgcn_mfma_f32_16x16x32_bf16(vf1, pb1, o[dt], 0, 0, 0);
        }
        __builtin_amdgcn_s_setprio(0);
    };

    STAGE(0, Ks0, Vs0);
    __syncthreads();   // implicit vmcnt(0): tile 0 ready

    for (int c = 0; c < NN / 64; c += 2) {
        STAGE(c + 1, Ks1, Vs1);            // hides under compute on buf0
        COMPUTE(Ks0, Vs0);
        __syncthreads();                   // drains vmcnt: buf1 ready, buf0 free
        if (c + 2 < NN / 64) STAGE(c + 2, Ks0, Vs0);
        COMPUTE(Ks1, Vs1);
        __syncthreads();                   // buf0 ready, buf1 free
    }

    int b = bh >> 4, h = bh & 15;
    // horizontal sum of the 4 chains, then reduce across quads
    float l = (lrow[0] + lrow[1]) + (lrow[2] + lrow[3]);
    l += __shfl_xor(l, 16, 64);
    l += __shfl_xor(l, 32, 64);
    float inv = 1.f / l;
    int grow = b * NN + q0 + wave * 16 + l16;
#pragma unroll
    for (int dt = 0; dt < 4; dt++) {
        u16x4 hv;
#pragma unroll
        for (int r = 0; r < 4; r++) hv[r] = f2bf(o[dt][r] * inv);
        int gcol = h * DD + dt * 16 + quad * 4;
        *(u16x4*)&Ob[(size_t)grow * CC + gcol] = hv;
    }
}

extern "C" void kernel_launch(void* const* d_in, const int* in_sizes, int n_in,
                              void* d_out, int out_size, void* d_ws, size_t ws_size,
                              hipStream_t stream) {
    const float* x      = (const float*)d_in[0];
    const float* w_qkv  = (const float*)d_in[1];
    const float* w_proj = (const float*)d_in[2];
    const float* b_proj = (const float*)d_in[3];
    float* out = (float*)d_out;

    u16* p = (u16*)d_ws;
    u16* Xb = p; p += (size_t)MM * CC;
    u16* Wq = p; p += (size_t)NQKV * CC;
    u16* Wp = p; p += (size_t)CC * CC;
    u16* Qb = p; p += (size_t)MM * CC;
    u16* Kb = p; p += (size_t)MM * CC;
    u16* Vb = p; p += (size_t)MM * CC;           // V^T [BH][D][N]
    u16* Ob = p; p += (size_t)MM * CC;

    k_prep<<<2048 + 3072 + 1024, 256, 0, stream>>>(x, w_qkv, w_proj, Xb, Wq, Wp);
    k_gemmq<<<dim3(NQKV / 192, MM / 256), 512, 0, stream>>>(Xb, Wq, Qb, Kb, Vb);
    // bh on x: linear id & 7 == bh & 7 -> one XCD per head group (K/V L2-resident)
    k_attn<<<dim3(BB * HH, NN / 128), 512, 0, stream>>>(Qb, Kb, Vb, Ob);
    // m on x: each XCD owns 8 contiguous m-panels of Ob
    k_gemmp<<<dim3(MM / 64, CC / 128), 256, 0, stream>>>(Ob, Wp, b_proj, out);
}